// Round 12
// baseline (41.022 us; speedup 1.0000x reference)
//
#include <hip/hip_runtime.h>

static constexpr int S_SYS   = 8;
static constexpr int E_PAIRS = 1000000;
static constexpr int N_A     = 20000;
static constexpr int NBINS   = 16;
static constexpr int BPS     = 32;                 // 256 blocks = 1/CU
static constexpr int BLK     = 1024;
static constexpr int UNR     = 2;                  // quad-groups in flight
static constexpr float SCALE   = 4194304.0f;       // 2^22
static constexpr float INV_SCL = 1.0f / 4194304.0f;
static constexpr float INV11 = 1.0f / 1.1f;

typedef unsigned u32x4 __attribute__((ext_vector_type(4)));  // nt-builtin-compatible

// Kernel 1: LDS-privatized u32 fixed-point coords, fire-and-forget ds_add_u32,
// branchless med3-clamped switching (poly exact at both clamp ends).
// Partial writes are NON-TEMPORAL: written once, read once by kde -> bypass
// L3 so the 128MB input stays L3-resident across graph replays.
__global__ __launch_bounds__(BLK, 4) void coord_lds_u32(
    const float* __restrict__ vec, const int* __restrict__ atom,
    unsigned* __restrict__ partial)
{
    __shared__ __align__(16) unsigned lc[N_A];        // 80 KB
    for (int i = threadIdx.x; i < N_A; i += BLK) lc[i] = 0u;
    __syncthreads();

    const int s = blockIdx.y;
    const int Q = E_PAIRS / 4;                        // 250,000 quad-groups/system
    const float4* vb = reinterpret_cast<const float4*>(vec) + (size_t)s * Q * 3;
    const int4*   ib = reinterpret_cast<const int4*>(atom) + (size_t)s * Q;

    const int W = BPS * BLK;                          // 32768
    for (int t = blockIdx.x * BLK + threadIdx.x; t < Q; t += W * UNR) {
        float4 A[UNR], B[UNR], C[UNR];
        int4   id[UNR];
        bool   ok[UNR];
        #pragma unroll
        for (int u = 0; u < UNR; ++u) {
            int tq = t + u * W;
            ok[u] = (tq < Q);
            if (ok[u]) {
                A[u] = vb[3 * tq]; B[u] = vb[3 * tq + 1]; C[u] = vb[3 * tq + 2];
                id[u] = ib[tq];
            }
        }
        #pragma unroll
        for (int u = 0; u < UNR; ++u) {
            if (!ok[u]) continue;
            float px[4] = {A[u].x, A[u].w, B[u].z, C[u].y};
            float py[4] = {A[u].y, B[u].x, B[u].w, C[u].z};
            float pz[4] = {A[u].z, B[u].y, C[u].x, C[u].w};
            int ids[4]  = {id[u].x, id[u].y, id[u].z, id[u].w};
            #pragma unroll
            for (int j = 0; j < 4; ++j) {
                float q = px[j]*px[j] + py[j]*py[j] + pz[j]*pz[j];
                float d = sqrtf(q);
                float y = (d - 4.4f) * INV11;         // (d - R1) / (R0 - R1)
                y = fminf(fmaxf(y, 0.0f), 1.0f);      // med3 clamp; poly exact at ends
                float uu = y - 1.0f;
                float z = uu * uu * (1.0f + 2.0f * y);
                atomicAdd(&lc[ids[j]], __float2uint_rn(z * SCALE));  // ds_add_u32
            }
        }
    }
    __syncthreads();

    u32x4* po = reinterpret_cast<u32x4*>(partial + ((size_t)s * BPS + blockIdx.x) * N_A);
    const u32x4* ls = reinterpret_cast<const u32x4*>(lc);
    for (int i = threadIdx.x; i < N_A / 4; i += BLK)
        __builtin_nontemporal_store(ls[i], &po[i]);    // nt: don't evict input from L3
}

// Kernel 2 (fast path): exact u32 sum of partials (nt loads) -> KDE.
__global__ __launch_bounds__(256) void kde_reduce_u32(
    const unsigned* __restrict__ partial, float* __restrict__ out)
{
    int s = blockIdx.y;
    int a = blockIdx.x * 256 + threadIdx.x;
    bool valid = (a < N_A);

    unsigned acc = 0u;
    if (valid) {
        const unsigned* p = partial + (size_t)s * BPS * N_A + a;
        #pragma unroll 8
        for (int b = 0; b < BPS; ++b)
            acc += __builtin_nontemporal_load(&p[(size_t)b * N_A]);
    }
    float c = (float)acc * INV_SCL;

    float vals[NBINS];
    #pragma unroll
    for (int k = 0; k < NBINS; ++k) {
        float d = c - (float)k;
        vals[k] = valid ? expf(-2.0f * d * d) : 0.0f;  // 0.5/SIGMA2 == 2
    }

    #pragma unroll
    for (int k = 0; k < NBINS; ++k) {
        #pragma unroll
        for (int off = 32; off > 0; off >>= 1)
            vals[k] += __shfl_down(vals[k], off, 64);
    }

    __shared__ float sbin[4][NBINS];
    int wave = threadIdx.x >> 6;
    int lane = threadIdx.x & 63;
    if (lane == 0) {
        #pragma unroll
        for (int k = 0; k < NBINS; ++k) sbin[wave][k] = vals[k];
    }
    __syncthreads();
    if (threadIdx.x < NBINS) {
        float v = sbin[0][threadIdx.x] + sbin[1][threadIdx.x]
                + sbin[2][threadIdx.x] + sbin[3][threadIdx.x];
        unsafeAtomicAdd(&out[s * NBINS + threadIdx.x], v);
    }
}

// ---------------- Fallback path (ws too small): global-atomic scatter --------
__global__ __launch_bounds__(256) void coord_scatter(
    const float* __restrict__ vec, const int* __restrict__ atom,
    float* __restrict__ coords)
{
    const int P4 = S_SYS * E_PAIRS / 4;
    int stride = gridDim.x * blockDim.x;
    for (int t = blockIdx.x * blockDim.x + threadIdx.x; t < P4; t += stride) {
        const float4* v4 = reinterpret_cast<const float4*>(vec) + 3ull * (unsigned)t;
        float4 A = v4[0], B = v4[1], C = v4[2];
        int4 id = reinterpret_cast<const int4*>(atom)[t];
        int s = (t * 4) / E_PAIRS;
        float* cs = coords + s * N_A;
        float px[4] = {A.x, A.w, B.z, C.y};
        float py[4] = {A.y, B.x, B.w, C.z};
        float pz[4] = {A.z, B.y, C.x, C.w};
        int ids[4]  = {id.x, id.y, id.z, id.w};
        #pragma unroll
        for (int j = 0; j < 4; ++j) {
            float d = sqrtf(px[j]*px[j] + py[j]*py[j] + pz[j]*pz[j]);
            float y = (d - 4.4f) / 1.1f;
            float z;
            if (y <= 0.0f)      z = 1.0f;
            else if (y >= 1.0f) z = 0.0f;
            else { float u = y - 1.0f; z = u * u * (1.0f + 2.0f * y); }
            if (z != 0.0f) unsafeAtomicAdd(&cs[ids[j]], z);
        }
    }
}

__global__ __launch_bounds__(256) void kde_reduce_f32(
    const float* __restrict__ coords, float* __restrict__ out)
{
    int s = blockIdx.y;
    int a = blockIdx.x * 256 + threadIdx.x;
    bool valid = (a < N_A);
    float c = valid ? coords[(size_t)s * N_A + a] : 0.0f;

    float vals[NBINS];
    #pragma unroll
    for (int k = 0; k < NBINS; ++k) {
        float d = c - (float)k;
        vals[k] = valid ? expf(-2.0f * d * d) : 0.0f;
    }
    #pragma unroll
    for (int k = 0; k < NBINS; ++k) {
        #pragma unroll
        for (int off = 32; off > 0; off >>= 1)
            vals[k] += __shfl_down(vals[k], off, 64);
    }
    __shared__ float sbin[4][NBINS];
    int wave = threadIdx.x >> 6;
    int lane = threadIdx.x & 63;
    if (lane == 0) {
        #pragma unroll
        for (int k = 0; k < NBINS; ++k) sbin[wave][k] = vals[k];
    }
    __syncthreads();
    if (threadIdx.x < NBINS) {
        float v = sbin[0][threadIdx.x] + sbin[1][threadIdx.x]
                + sbin[2][threadIdx.x] + sbin[3][threadIdx.x];
        unsafeAtomicAdd(&out[s * NBINS + threadIdx.x], v);
    }
}

extern "C" void kernel_launch(void* const* d_in, const int* in_sizes, int n_in,
                              void* d_out, int out_size, void* d_ws, size_t ws_size,
                              hipStream_t stream) {
    const float* vec  = (const float*)d_in[0];   // [S,E,3] f32
    const int*   atom = (const int*)d_in[1];     // [S,E] i32
    float* out = (float*)d_out;                  // [S,16] f32

    (void)hipMemsetAsync(out, 0, (size_t)S_SYS * NBINS * sizeof(float), stream);

    const size_t need = (size_t)S_SYS * BPS * N_A * sizeof(unsigned);  // 20.5 MB
    dim3 g2((N_A + 255) / 256, S_SYS);

    if (ws_size >= need) {
        unsigned* ws = (unsigned*)d_ws;
        dim3 g1(BPS, S_SYS);                      // 256 blocks
        coord_lds_u32<<<g1, BLK, 0, stream>>>(vec, atom, ws);
        kde_reduce_u32<<<g2, 256, 0, stream>>>(ws, out);
    } else {
        float* ws = (float*)d_ws;
        (void)hipMemsetAsync(ws, 0, (size_t)S_SYS * N_A * sizeof(float), stream);
        coord_scatter<<<2048, 256, 0, stream>>>(vec, atom, ws);
        kde_reduce_f32<<<g2, 256, 0, stream>>>(ws, out);
    }
}

// Round 13
// 33.742 us; speedup vs baseline: 1.2157x; 1.2157x over previous
//
#include <hip/hip_runtime.h>

static constexpr int S_SYS   = 8;
static constexpr int E_PAIRS = 1000000;
static constexpr int N_A     = 20000;
static constexpr int NBINS   = 16;
static constexpr int BPS     = 32;                 // 256 blocks = 1/CU
static constexpr int BLK     = 1024;
static constexpr int UNR     = 2;                  // quad-groups in flight
static constexpr float SCALE   = 1024.0f;          // 2^10 (u16 partials; max sum ~40*1024 << 65535)
static constexpr float INV_SCL = 1.0f / 1024.0f;
static constexpr float INV11 = 1.0f / 1.1f;

typedef unsigned u32x4 __attribute__((ext_vector_type(4)));

// Kernel 1: LDS-privatized u32 fixed-point coords (ds_add_u32, fire-and-forget),
// branchless med3-clamped switching, raw v_sqrt. Partials packed to u16 on
// store (halves traffic). Block 0 of each system also zero-stores the output
// bins, removing the separate memset dispatch.
__global__ __launch_bounds__(BLK, 4) void coord_lds_u32(
    const float* __restrict__ vec, const int* __restrict__ atom,
    unsigned short* __restrict__ partial, float* __restrict__ out)
{
    __shared__ __align__(16) unsigned lc[N_A];        // 80 KB
    for (int i = threadIdx.x; i < N_A; i += BLK) lc[i] = 0u;

    const int s = blockIdx.y;
    if (blockIdx.x == 0 && threadIdx.x < NBINS)       // zero out bins for kde's atomics
        out[s * NBINS + threadIdx.x] = 0.0f;
    __syncthreads();

    const int Q = E_PAIRS / 4;                        // 250,000 quad-groups/system
    const float4* vb = reinterpret_cast<const float4*>(vec) + (size_t)s * Q * 3;
    const int4*   ib = reinterpret_cast<const int4*>(atom) + (size_t)s * Q;

    const int W = BPS * BLK;                          // 32768
    for (int t = blockIdx.x * BLK + threadIdx.x; t < Q; t += W * UNR) {
        float4 A[UNR], B[UNR], C[UNR];
        int4   id[UNR];
        bool   ok[UNR];
        #pragma unroll
        for (int u = 0; u < UNR; ++u) {
            int tq = t + u * W;
            ok[u] = (tq < Q);
            if (ok[u]) {
                A[u] = vb[3 * tq]; B[u] = vb[3 * tq + 1]; C[u] = vb[3 * tq + 2];
                id[u] = ib[tq];
            }
        }
        #pragma unroll
        for (int u = 0; u < UNR; ++u) {
            if (!ok[u]) continue;
            float px[4] = {A[u].x, A[u].w, B[u].z, C[u].y};
            float py[4] = {A[u].y, B[u].x, B[u].w, C[u].z};
            float pz[4] = {A[u].z, B[u].y, C[u].x, C[u].w};
            int ids[4]  = {id[u].x, id[u].y, id[u].z, id[u].w};
            #pragma unroll
            for (int j = 0; j < 4; ++j) {
                float q = px[j]*px[j] + py[j]*py[j] + pz[j]*pz[j];
                float d = __builtin_amdgcn_sqrtf(q);  // raw v_sqrt_f32, no fixups
                float y = (d - 4.4f) * INV11;         // (d - R1) / (R0 - R1)
                y = fminf(fmaxf(y, 0.0f), 1.0f);      // clamp; poly exact at ends
                float uu = y - 1.0f;
                float z = uu * uu * (1.0f + 2.0f * y);
                atomicAdd(&lc[ids[j]], __float2uint_rn(z * SCALE));  // ds_add_u32
            }
        }
    }
    __syncthreads();

    // pack u32 -> u16 pairs, nt-store 8 atoms per 16B
    u32x4* po = reinterpret_cast<u32x4*>(partial + ((size_t)s * BPS + blockIdx.x) * N_A);
    for (int i = threadIdx.x; i < N_A / 8; i += BLK) {
        u32x4 v;
        #pragma unroll
        for (int k = 0; k < 4; ++k)
            v[k] = (lc[8 * i + 2 * k] & 0xFFFFu) | (lc[8 * i + 2 * k + 1] << 16);
        __builtin_nontemporal_store(v, &po[i]);
    }
}

// Kernel 2: sum u16 partials (u32 loads cover 2 atoms/thread, coalesced),
// KDE, 16 atomics/block into pre-zeroed out.
__global__ __launch_bounds__(256) void kde_reduce_u16(
    const unsigned* __restrict__ partial32, float* __restrict__ out)
{
    int s = blockIdx.y;
    int a0 = blockIdx.x * 512 + 2 * threadIdx.x;      // this thread: atoms a0, a0+1
    bool valid = (a0 < N_A);

    unsigned acc0 = 0u, acc1 = 0u;
    if (valid) {
        const unsigned* p = partial32 + ((size_t)s * BPS * N_A + a0) / 2;
        #pragma unroll 8
        for (int b = 0; b < BPS; ++b) {
            unsigned v = __builtin_nontemporal_load(&p[(size_t)b * (N_A / 2)]);
            acc0 += v & 0xFFFFu;
            acc1 += v >> 16;
        }
    }
    float c0 = (float)acc0 * INV_SCL;
    float c1 = (float)acc1 * INV_SCL;

    float vals[NBINS];
    #pragma unroll
    for (int k = 0; k < NBINS; ++k) {
        float d0 = c0 - (float)k, d1 = c1 - (float)k;
        vals[k] = valid ? (expf(-2.0f * d0 * d0) + expf(-2.0f * d1 * d1)) : 0.0f;
    }

    #pragma unroll
    for (int k = 0; k < NBINS; ++k) {
        #pragma unroll
        for (int off = 32; off > 0; off >>= 1)
            vals[k] += __shfl_down(vals[k], off, 64);
    }

    __shared__ float sbin[4][NBINS];
    int wave = threadIdx.x >> 6;
    int lane = threadIdx.x & 63;
    if (lane == 0) {
        #pragma unroll
        for (int k = 0; k < NBINS; ++k) sbin[wave][k] = vals[k];
    }
    __syncthreads();
    if (threadIdx.x < NBINS) {
        float v = sbin[0][threadIdx.x] + sbin[1][threadIdx.x]
                + sbin[2][threadIdx.x] + sbin[3][threadIdx.x];
        unsafeAtomicAdd(&out[s * NBINS + threadIdx.x], v);
    }
}

// ---------------- Fallback path (ws too small): global-atomic scatter --------
__global__ __launch_bounds__(256) void coord_scatter(
    const float* __restrict__ vec, const int* __restrict__ atom,
    float* __restrict__ coords)
{
    const int P4 = S_SYS * E_PAIRS / 4;
    int stride = gridDim.x * blockDim.x;
    for (int t = blockIdx.x * blockDim.x + threadIdx.x; t < P4; t += stride) {
        const float4* v4 = reinterpret_cast<const float4*>(vec) + 3ull * (unsigned)t;
        float4 A = v4[0], B = v4[1], C = v4[2];
        int4 id = reinterpret_cast<const int4*>(atom)[t];
        int s = (t * 4) / E_PAIRS;
        float* cs = coords + s * N_A;
        float px[4] = {A.x, A.w, B.z, C.y};
        float py[4] = {A.y, B.x, B.w, C.z};
        float pz[4] = {A.z, B.y, C.x, C.w};
        int ids[4]  = {id.x, id.y, id.z, id.w};
        #pragma unroll
        for (int j = 0; j < 4; ++j) {
            float d = sqrtf(px[j]*px[j] + py[j]*py[j] + pz[j]*pz[j]);
            float y = (d - 4.4f) / 1.1f;
            float z;
            if (y <= 0.0f)      z = 1.0f;
            else if (y >= 1.0f) z = 0.0f;
            else { float u = y - 1.0f; z = u * u * (1.0f + 2.0f * y); }
            if (z != 0.0f) unsafeAtomicAdd(&cs[ids[j]], z);
        }
    }
}

__global__ __launch_bounds__(256) void kde_reduce_f32(
    const float* __restrict__ coords, float* __restrict__ out)
{
    int s = blockIdx.y;
    int a = blockIdx.x * 256 + threadIdx.x;
    bool valid = (a < N_A);
    float c = valid ? coords[(size_t)s * N_A + a] : 0.0f;

    float vals[NBINS];
    #pragma unroll
    for (int k = 0; k < NBINS; ++k) {
        float d = c - (float)k;
        vals[k] = valid ? expf(-2.0f * d * d) : 0.0f;
    }
    #pragma unroll
    for (int k = 0; k < NBINS; ++k) {
        #pragma unroll
        for (int off = 32; off > 0; off >>= 1)
            vals[k] += __shfl_down(vals[k], off, 64);
    }
    __shared__ float sbin[4][NBINS];
    int wave = threadIdx.x >> 6;
    int lane = threadIdx.x & 63;
    if (lane == 0) {
        #pragma unroll
        for (int k = 0; k < NBINS; ++k) sbin[wave][k] = vals[k];
    }
    __syncthreads();
    if (threadIdx.x < NBINS) {
        float v = sbin[0][threadIdx.x] + sbin[1][threadIdx.x]
                + sbin[2][threadIdx.x] + sbin[3][threadIdx.x];
        unsafeAtomicAdd(&out[s * NBINS + threadIdx.x], v);
    }
}

extern "C" void kernel_launch(void* const* d_in, const int* in_sizes, int n_in,
                              void* d_out, int out_size, void* d_ws, size_t ws_size,
                              hipStream_t stream) {
    const float* vec  = (const float*)d_in[0];   // [S,E,3] f32
    const int*   atom = (const int*)d_in[1];     // [S,E] i32
    float* out = (float*)d_out;                  // [S,16] f32

    const size_t need = (size_t)S_SYS * BPS * N_A * sizeof(unsigned short);  // 10.24 MB

    if (ws_size >= need) {
        unsigned short* ws = (unsigned short*)d_ws;
        dim3 g1(BPS, S_SYS);                      // 256 blocks; also zeroes out
        coord_lds_u32<<<g1, BLK, 0, stream>>>(vec, atom, ws, out);
        dim3 g2((N_A + 511) / 512, S_SYS);        // 40 x 8 blocks, 2 atoms/thread
        kde_reduce_u16<<<g2, 256, 0, stream>>>((const unsigned*)ws, out);
    } else {
        float* ws = (float*)d_ws;
        (void)hipMemsetAsync(out, 0, (size_t)S_SYS * NBINS * sizeof(float), stream);
        (void)hipMemsetAsync(ws, 0, (size_t)S_SYS * N_A * sizeof(float), stream);
        coord_scatter<<<2048, 256, 0, stream>>>(vec, atom, ws);
        dim3 g2f((N_A + 255) / 256, S_SYS);
        kde_reduce_f32<<<g2f, 256, 0, stream>>>(ws, out);
    }
}

// Round 14
// 33.381 us; speedup vs baseline: 1.2289x; 1.0108x over previous
//
#include <hip/hip_runtime.h>

static constexpr int S_SYS   = 8;
static constexpr int E_PAIRS = 1000000;
static constexpr int N_A     = 20000;
static constexpr int NBINS   = 16;
static constexpr int BPS     = 32;                 // 256 blocks = 1/CU
static constexpr int BLK     = 1024;
static constexpr int UNR     = 2;                  // quad-groups in flight
static constexpr float SCALE   = 1024.0f;          // 2^10 (u16 partials)
static constexpr float INV_SCL = 1.0f / 1024.0f;
static constexpr float INV11 = 1.0f / 1.1f;

typedef unsigned u32x4 __attribute__((ext_vector_type(4)));

// Kernel 1: LDS-privatized u32 fixed-point coords, fire-and-forget ds_add_u32,
// branchless med3-clamped switching, raw v_sqrt. ds_add predicated on fx!=0:
// ~15% of lanes (z==0 pairs) are exec-masked off -> no LDS bank slots consumed.
// Partials packed to u16; block 0 per system zero-stores out bins (no memset).
__global__ __launch_bounds__(BLK, 4) void coord_lds_u32(
    const float* __restrict__ vec, const int* __restrict__ atom,
    unsigned short* __restrict__ partial, float* __restrict__ out)
{
    __shared__ __align__(16) unsigned lc[N_A];        // 80 KB
    for (int i = threadIdx.x; i < N_A; i += BLK) lc[i] = 0u;

    const int s = blockIdx.y;
    if (blockIdx.x == 0 && threadIdx.x < NBINS)       // zero out bins for kde's atomics
        out[s * NBINS + threadIdx.x] = 0.0f;
    __syncthreads();

    const int Q = E_PAIRS / 4;                        // 250,000 quad-groups/system
    const float4* vb = reinterpret_cast<const float4*>(vec) + (size_t)s * Q * 3;
    const int4*   ib = reinterpret_cast<const int4*>(atom) + (size_t)s * Q;

    const int W = BPS * BLK;                          // 32768
    for (int t = blockIdx.x * BLK + threadIdx.x; t < Q; t += W * UNR) {
        float4 A[UNR], B[UNR], C[UNR];
        int4   id[UNR];
        bool   ok[UNR];
        #pragma unroll
        for (int u = 0; u < UNR; ++u) {
            int tq = t + u * W;
            ok[u] = (tq < Q);
            if (ok[u]) {
                A[u] = vb[3 * tq]; B[u] = vb[3 * tq + 1]; C[u] = vb[3 * tq + 2];
                id[u] = ib[tq];
            }
        }
        #pragma unroll
        for (int u = 0; u < UNR; ++u) {
            if (!ok[u]) continue;
            float px[4] = {A[u].x, A[u].w, B[u].z, C[u].y};
            float py[4] = {A[u].y, B[u].x, B[u].w, C[u].z};
            float pz[4] = {A[u].z, B[u].y, C[u].x, C[u].w};
            int ids[4]  = {id[u].x, id[u].y, id[u].z, id[u].w};
            #pragma unroll
            for (int j = 0; j < 4; ++j) {
                float q = px[j]*px[j] + py[j]*py[j] + pz[j]*pz[j];
                float d = __builtin_amdgcn_sqrtf(q);  // raw v_sqrt_f32
                float y = (d - 4.4f) * INV11;         // (d - R1) / (R0 - R1)
                y = fminf(fmaxf(y, 0.0f), 1.0f);      // med3 clamp; poly exact at ends
                float uu = y - 1.0f;
                float z = uu * uu * (1.0f + 2.0f * y);
                unsigned fx = __float2uint_rn(z * SCALE);
                if (fx) atomicAdd(&lc[ids[j]], fx);   // predicated ds_add_u32
            }
        }
    }
    __syncthreads();

    // pack u32 -> u16 pairs, nt-store 8 atoms per 16B
    u32x4* po = reinterpret_cast<u32x4*>(partial + ((size_t)s * BPS + blockIdx.x) * N_A);
    for (int i = threadIdx.x; i < N_A / 8; i += BLK) {
        u32x4 v;
        #pragma unroll
        for (int k = 0; k < 4; ++k)
            v[k] = (lc[8 * i + 2 * k] & 0xFFFFu) | (lc[8 * i + 2 * k + 1] << 16);
        __builtin_nontemporal_store(v, &po[i]);
    }
}

// Kernel 2: sum u16 partials (u32 loads, 2 atoms/thread), fast-exp KDE,
// 16 atomics/block into pre-zeroed out.
__global__ __launch_bounds__(256) void kde_reduce_u16(
    const unsigned* __restrict__ partial32, float* __restrict__ out)
{
    int s = blockIdx.y;
    int a0 = blockIdx.x * 512 + 2 * threadIdx.x;      // atoms a0, a0+1
    bool valid = (a0 < N_A);

    unsigned acc0 = 0u, acc1 = 0u;
    if (valid) {
        const unsigned* p = partial32 + ((size_t)s * BPS * N_A + a0) / 2;
        #pragma unroll 8
        for (int b = 0; b < BPS; ++b) {
            unsigned v = __builtin_nontemporal_load(&p[(size_t)b * (N_A / 2)]);
            acc0 += v & 0xFFFFu;
            acc1 += v >> 16;
        }
    }
    float c0 = (float)acc0 * INV_SCL;
    float c1 = (float)acc1 * INV_SCL;

    float vals[NBINS];
    #pragma unroll
    for (int k = 0; k < NBINS; ++k) {
        float d0 = c0 - (float)k, d1 = c1 - (float)k;
        vals[k] = valid ? (__expf(-2.0f * d0 * d0) + __expf(-2.0f * d1 * d1)) : 0.0f;
    }

    #pragma unroll
    for (int k = 0; k < NBINS; ++k) {
        #pragma unroll
        for (int off = 32; off > 0; off >>= 1)
            vals[k] += __shfl_down(vals[k], off, 64);
    }

    __shared__ float sbin[4][NBINS];
    int wave = threadIdx.x >> 6;
    int lane = threadIdx.x & 63;
    if (lane == 0) {
        #pragma unroll
        for (int k = 0; k < NBINS; ++k) sbin[wave][k] = vals[k];
    }
    __syncthreads();
    if (threadIdx.x < NBINS) {
        float v = sbin[0][threadIdx.x] + sbin[1][threadIdx.x]
                + sbin[2][threadIdx.x] + sbin[3][threadIdx.x];
        unsafeAtomicAdd(&out[s * NBINS + threadIdx.x], v);
    }
}

// ---------------- Fallback path (ws too small): global-atomic scatter --------
__global__ __launch_bounds__(256) void coord_scatter(
    const float* __restrict__ vec, const int* __restrict__ atom,
    float* __restrict__ coords)
{
    const int P4 = S_SYS * E_PAIRS / 4;
    int stride = gridDim.x * blockDim.x;
    for (int t = blockIdx.x * blockDim.x + threadIdx.x; t < P4; t += stride) {
        const float4* v4 = reinterpret_cast<const float4*>(vec) + 3ull * (unsigned)t;
        float4 A = v4[0], B = v4[1], C = v4[2];
        int4 id = reinterpret_cast<const int4*>(atom)[t];
        int s = (t * 4) / E_PAIRS;
        float* cs = coords + s * N_A;
        float px[4] = {A.x, A.w, B.z, C.y};
        float py[4] = {A.y, B.x, B.w, C.z};
        float pz[4] = {A.z, B.y, C.x, C.w};
        int ids[4]  = {id.x, id.y, id.z, id.w};
        #pragma unroll
        for (int j = 0; j < 4; ++j) {
            float d = sqrtf(px[j]*px[j] + py[j]*py[j] + pz[j]*pz[j]);
            float y = (d - 4.4f) / 1.1f;
            float z;
            if (y <= 0.0f)      z = 1.0f;
            else if (y >= 1.0f) z = 0.0f;
            else { float u = y - 1.0f; z = u * u * (1.0f + 2.0f * y); }
            if (z != 0.0f) unsafeAtomicAdd(&cs[ids[j]], z);
        }
    }
}

__global__ __launch_bounds__(256) void kde_reduce_f32(
    const float* __restrict__ coords, float* __restrict__ out)
{
    int s = blockIdx.y;
    int a = blockIdx.x * 256 + threadIdx.x;
    bool valid = (a < N_A);
    float c = valid ? coords[(size_t)s * N_A + a] : 0.0f;

    float vals[NBINS];
    #pragma unroll
    for (int k = 0; k < NBINS; ++k) {
        float d = c - (float)k;
        vals[k] = valid ? expf(-2.0f * d * d) : 0.0f;
    }
    #pragma unroll
    for (int k = 0; k < NBINS; ++k) {
        #pragma unroll
        for (int off = 32; off > 0; off >>= 1)
            vals[k] += __shfl_down(vals[k], off, 64);
    }
    __shared__ float sbin[4][NBINS];
    int wave = threadIdx.x >> 6;
    int lane = threadIdx.x & 63;
    if (lane == 0) {
        #pragma unroll
        for (int k = 0; k < NBINS; ++k) sbin[wave][k] = vals[k];
    }
    __syncthreads();
    if (threadIdx.x < NBINS) {
        float v = sbin[0][threadIdx.x] + sbin[1][threadIdx.x]
                + sbin[2][threadIdx.x] + sbin[3][threadIdx.x];
        unsafeAtomicAdd(&out[s * NBINS + threadIdx.x], v);
    }
}

extern "C" void kernel_launch(void* const* d_in, const int* in_sizes, int n_in,
                              void* d_out, int out_size, void* d_ws, size_t ws_size,
                              hipStream_t stream) {
    const float* vec  = (const float*)d_in[0];   // [S,E,3] f32
    const int*   atom = (const int*)d_in[1];     // [S,E] i32
    float* out = (float*)d_out;                  // [S,16] f32

    const size_t need = (size_t)S_SYS * BPS * N_A * sizeof(unsigned short);  // 10.24 MB

    if (ws_size >= need) {
        unsigned short* ws = (unsigned short*)d_ws;
        dim3 g1(BPS, S_SYS);                      // 256 blocks; also zeroes out
        coord_lds_u32<<<g1, BLK, 0, stream>>>(vec, atom, ws, out);
        dim3 g2((N_A + 511) / 512, S_SYS);        // 40 x 8 blocks, 2 atoms/thread
        kde_reduce_u16<<<g2, 256, 0, stream>>>((const unsigned*)ws, out);
    } else {
        float* ws = (float*)d_ws;
        (void)hipMemsetAsync(out, 0, (size_t)S_SYS * NBINS * sizeof(float), stream);
        (void)hipMemsetAsync(ws, 0, (size_t)S_SYS * N_A * sizeof(float), stream);
        coord_scatter<<<2048, 256, 0, stream>>>(vec, atom, ws);
        dim3 g2f((N_A + 255) / 256, S_SYS);
        kde_reduce_f32<<<g2f, 256, 0, stream>>>(ws, out);
    }
}